// Round 17
// baseline (152.130 us; speedup 1.0000x reference)
//
#include <hip/hip_runtime.h>
#include <hip/hip_bf16.h>

#define V_     32000
#define NSEG_  2
#define MAXLEN_ 512
#define D_     768
#define H_     12
#define HS_    64
#define B_     16
#define T_     512
#define NMASK_ 20
#define LN_EPS_ 1e-5f

typedef __hip_bfloat16 bf16;
typedef unsigned short ushortT;
typedef __attribute__((ext_vector_type(8))) short short8;
typedef __attribute__((ext_vector_type(4))) float f32x4;
typedef __attribute__((ext_vector_type(4))) unsigned int u32x4;
typedef __attribute__((ext_vector_type(4))) unsigned short u16x4;

__device__ __forceinline__ ushortT f2bu(float f) {
    bf16 h = __float2bfloat16(f);
    return *reinterpret_cast<ushortT*>(&h);
}

// ---------------- Kernel 1: embedding gather + LayerNorm -> xb (bf16), vectorized ----------------
__global__ void k_embed_ln(const int* __restrict__ seq, const int* __restrict__ seg,
                           const float* __restrict__ tok, const float* __restrict__ sege,
                           const float* __restrict__ pos, const float* __restrict__ g,
                           const float* __restrict__ bb, ushortT* __restrict__ xb) {
    int row = blockIdx.x;          // b*T + t
    int t = row & (T_ - 1);
    int tid = threadIdx.x;         // 0..191
    __shared__ float wsum[3], wsq[3];

    int sidx = seq[row];
    int gidx = seg[row];

    f32x4 e = *(const f32x4*)(tok  + (size_t)sidx * D_ + tid * 4);
    f32x4 e2 = *(const f32x4*)(sege + (size_t)gidx * D_ + tid * 4);
    f32x4 e3 = *(const f32x4*)(pos  + (size_t)t    * D_ + tid * 4);
    e = e + e2 + e3;

    float ls = e.x + e.y + e.z + e.w;
    float lq = e.x * e.x + e.y * e.y + e.z * e.z + e.w * e.w;
    #pragma unroll
    for (int o = 32; o > 0; o >>= 1) {
        ls += __shfl_down(ls, o);
        lq += __shfl_down(lq, o);
    }
    if ((tid & 63) == 0) { wsum[tid >> 6] = ls; wsq[tid >> 6] = lq; }
    __syncthreads();
    float s  = wsum[0] + wsum[1] + wsum[2];
    float sq = wsq[0] + wsq[1] + wsq[2];
    float mean = s * (1.0f / D_);
    float var  = sq * (1.0f / D_) - mean * mean;
    float rstd = rsqrtf(var + LN_EPS_);

    f32x4 g4 = *(const f32x4*)(g  + tid * 4);
    f32x4 b4 = *(const f32x4*)(bb + tid * 4);
    f32x4 x4;
    x4.x = (e.x - mean) * rstd * g4.x + b4.x;
    x4.y = (e.y - mean) * rstd * g4.y + b4.y;
    x4.z = (e.z - mean) * rstd * g4.z + b4.z;
    x4.w = (e.w - mean) * rstd * g4.w + b4.w;
    u16x4 ov = {f2bu(x4.x), f2bu(x4.y), f2bu(x4.z), f2bu(x4.w)};
    *(u16x4*)(xb + (size_t)row * D_ + tid * 4) = ov;
}

// ---------------- Prep: WcatT[n][k] bf16; grid (36, 12) ----------------
__global__ void k_prep_wqkv(const float* __restrict__ Wq, const float* __restrict__ Wk,
                            const float* __restrict__ Wv, ushortT* __restrict__ Wt) {
    int blk = blockIdx.x;
    int which = blk / H_, h = blk % H_;
    int kc = blockIdx.y * 64;
    const float* W = (which == 0) ? Wq : (which == 1) ? Wk : Wv;  // [H][D][HS]
    __shared__ float tile[64][65];
    int tid = threadIdx.x, c = tid & 63, rgrp = tid >> 6;
    for (int kk = rgrp; kk < 64; kk += 4)
        tile[kk][c] = W[((size_t)h * D_ + kc + kk) * HS_ + c];
    __syncthreads();
    for (int ss = rgrp; ss < 64; ss += 4)
        Wt[((size_t)which * D_ + h * HS_ + ss) * D_ + kc + c] = f2bu(tile[c][ss]);
}

// ---------------- Prep: gather masked rows -> xm[384][768] bf16 (zero pad) ----------------
__global__ void k_gather_xm(const float* __restrict__ x2, const int* __restrict__ masked_pos,
                            ushortT* __restrict__ xm) {
    int r = blockIdx.x;      // 0..383
    int tid = threadIdx.x;
    if (r < B_ * NMASK_) {
        int b = r / NMASK_, m = r % NMASK_;
        int t = masked_pos[b * NMASK_ + m];
        for (int d = tid; d < D_; d += 256)
            xm[(size_t)r * D_ + d] = f2bu(x2[((size_t)b * T_ + t) * D_ + d]);
    } else {
        for (int d = tid; d < D_; d += 256)
            xm[(size_t)r * D_ + d] = 0;
    }
}

// ---------------- shared staging helpers ----------------
__device__ __forceinline__ void stage_chunk(const ushortT* __restrict__ src, int row_stride,
                                            int r0, int k0, ushortT* dst, int w, int lane) {
    #pragma unroll
    for (int i = 0; i < 2; ++i) {
        int slot = w * 64 + lane + i * 256;    // 0..511
        int row = slot >> 2;
        int cs = ((slot & 3) ^ (row & 3)) * 8; // swizzled source chunk (rule 21)
        __builtin_amdgcn_global_load_lds(
            (const __attribute__((address_space(1))) void*)(src + (size_t)(r0 + row) * row_stride + k0 + cs),
            (__attribute__((address_space(3))) void*)(dst + (w * 64 + i * 256) * 8),
            16, 0, 0);
    }
}

// ---------------- 2-phase double-buffered MFMA 128x128 GEMM body, chunk-swizzled ----------------
__device__ __forceinline__ void gemm128_2ph(const ushortT* __restrict__ A,
                                            const ushortT* __restrict__ Bt,
                                            int m0, int n0,
                                            ushortT* lds,       // >= 16384 ushorts
                                            f32x4 acc[4][4]) {
    const int NT = D_ / 32;   // 24
    int tid = threadIdx.x;
    int lane = tid & 63, w = tid >> 6;
    int wr = (w >> 1) * 64, wc = (w & 1) * 64;
    int l16 = lane & 15, lk = lane >> 4;
    int sw = (lk ^ (l16 & 3)) * 8;            // swizzled read chunk offset (ushorts)

    #pragma unroll
    for (int i = 0; i < 4; ++i)
        #pragma unroll
        for (int j = 0; j < 4; ++j)
            acc[i][j] = (f32x4){0.f, 0.f, 0.f, 0.f};

    stage_chunk(A, D_, m0, 0, lds, w, lane);
    stage_chunk(Bt, D_, n0, 0, lds + 4096, w, lane);
    asm volatile("s_waitcnt vmcnt(0)" ::: "memory");
    __builtin_amdgcn_s_barrier();

    for (int t = 0; t < NT; ++t) {
        int cur = (t & 1) * 8192;
        int nxt = 8192 - cur;
        if (t + 1 < NT) {
            stage_chunk(A, D_, m0, (t + 1) * 32, lds + nxt, w, lane);
            stage_chunk(Bt, D_, n0, (t + 1) * 32, lds + nxt + 4096, w, lane);
        }

        const ushortT* Asc = lds + cur;
        const ushortT* Bsc = lds + cur + 4096;
        short8 a[4], bfr[4];
        #pragma unroll
        for (int i = 0; i < 4; ++i) {
            a[i]   = *(const short8*)(Asc + (wr + i * 16 + l16) * 32 + sw);
            bfr[i] = *(const short8*)(Bsc + (wc + i * 16 + l16) * 32 + sw);
        }
        #pragma unroll
        for (int i = 0; i < 4; ++i)
            #pragma unroll
            for (int j = 0; j < 4; ++j)
                acc[i][j] = __builtin_amdgcn_mfma_f32_16x16x32_bf16(a[i], bfr[j], acc[i][j], 0, 0, 0);

        asm volatile("s_waitcnt vmcnt(0)" ::: "memory");
        __builtin_amdgcn_s_barrier();
    }
}

// ---------------- QKV GEMM: XCD-swizzled grid 1152; LDS-transposed coalesced epilogue ----------------
__global__ __launch_bounds__(256, 4)
void k_gemm_qkv(const ushortT* __restrict__ xb, const ushortT* __restrict__ WcatT,
                ushortT* __restrict__ qb, ushortT* __restrict__ kb,
                ushortT* __restrict__ vb) {
    __shared__ ushortT lds[128 * 136];   // gemm uses first 16384; epilogue uses all
    f32x4 acc[4][4];
    int lin = (blockIdx.x & 7) * 144 + (blockIdx.x >> 3);
    int n0 = (lin % 18) * 128, m0 = (lin / 18) * 128;
    gemm128_2ph(xb, WcatT, m0, n0, lds, acc);

    int tid = threadIdx.x;
    int lane = tid & 63, w = tid >> 6;
    int wr = (w >> 1) * 64, wc = (w & 1) * 64;
    int l16 = lane & 15, lk = lane >> 4;

    #pragma unroll
    for (int j = 0; j < 4; ++j) {
        int n = wc + j * 16 + l16;
        #pragma unroll
        for (int i = 0; i < 4; ++i) {
            #pragma unroll
            for (int r = 0; r < 4; ++r) {
                int m = wr + i * 16 + lk * 4 + r;
                lds[m * 136 + n] = f2bu(acc[i][j][r]);
            }
        }
    }
    __syncthreads();

    int which = n0 / D_;                 // uniform per block
    int nrem0 = n0 - which * D_;
    ushortT* outp = (which == 0) ? qb : (which == 1) ? kb : vb;
    int b = m0 >> 9;
    int t0 = m0 & (T_ - 1);
    #pragma unroll
    for (int p = 0; p < 8; ++p) {
        int chunk = p * 256 + tid;       // 0..2047
        int row = chunk >> 4;            // m local
        int nc = (chunk & 15) * 8;       // n ushort offset
        int h = (nrem0 >> 6) + (nc >> 6);
        int s0 = nc & 63;
        u32x4 v = *(const u32x4*)(&lds[row * 136 + nc]);
        *(u32x4*)(outp + ((size_t)(b * H_ + h) * T_ + (t0 + row)) * HS_ + s0) = v;
    }
}

// ---------------- LM GEMM (fused transpose), XCD-grouped by n-tile ----------------
// B-staging: each thread owns a 4k x 4n block -> 4 x dwordx4 loads (coalesced along n),
// cvt, 4 x ds_write_b64 transposed into Bs[n][36]. 4 VMEM ops/K-step (was 16).
__global__ __launch_bounds__(256, 4)
void k_gemm_lm(const ushortT* __restrict__ xm, const float* __restrict__ Wlm,
               const float* __restrict__ blm, float* __restrict__ out) {
    const int NT = D_ / 32;   // 24
    __shared__ ushortT As[2][4096];
    __shared__ ushortT Bs[2][128 * 36];
    f32x4 acc[4][4];

    int bid = blockIdx.x;            // 0..749
    const int q = 93, r = 6;
    int xcd = bid & 7, idx = bid >> 3;
    int lin = (xcd < r) ? xcd * (q + 1) + idx : r * (q + 1) + (xcd - r) * q + idx;
    int nt = lin / 3, mt = lin - nt * 3;
    int m0 = mt * 128, n0 = nt * 128;

    int tid = threadIdx.x;
    int lane = tid & 63, w = tid >> 6;
    int wr = (w >> 1) * 64, wc = (w & 1) * 64;
    int l16 = lane & 15, lk = lane >> 4;
    int sw = (lk ^ (l16 & 3)) * 8;
    int n4 = (tid & 31) * 4;         // 4 consecutive n columns
    int kq = (tid >> 5) * 4;         // 4 consecutive k rows (0..28)

    #pragma unroll
    for (int i = 0; i < 4; ++i)
        #pragma unroll
        for (int j = 0; j < 4; ++j)
            acc[i][j] = (f32x4){0.f, 0.f, 0.f, 0.f};

    // prologue: tile 0
    stage_chunk(xm, D_, m0, 0, As[0], w, lane);
    {
        f32x4 bw[4];
        #pragma unroll
        for (int rr = 0; rr < 4; ++rr)
            bw[rr] = *(const f32x4*)(Wlm + (size_t)(kq + rr) * V_ + n0 + n4);
        #pragma unroll
        for (int c = 0; c < 4; ++c) {
            u16x4 pk = {f2bu(bw[0][c]), f2bu(bw[1][c]), f2bu(bw[2][c]), f2bu(bw[3][c])};
            *(u16x4*)(&Bs[0][(n4 + c) * 36 + kq]) = pk;
        }
    }
    asm volatile("s_waitcnt vmcnt(0) lgkmcnt(0)" ::: "memory");
    __builtin_amdgcn_s_barrier();

    for (int t = 0; t < NT; ++t) {
        int cur = t & 1, nx = cur ^ 1;
        f32x4 bw[4];
        if (t + 1 < NT) {
            stage_chunk(xm, D_, m0, (t + 1) * 32, As[nx], w, lane);
            int k0 = (t + 1) * 32;
            #pragma unroll
            for (int rr = 0; rr < 4; ++rr)
                bw[rr] = *(const f32x4*)(Wlm + (size_t)(k0 + kq + rr) * V_ + n0 + n4);
        }

        short8 a[4], bfr[4];
        #pragma unroll
        for (int i = 0; i < 4; ++i) {
            a[i]   = *(const short8*)(&As[cur][(wr + i * 16 + l16) * 32 + sw]);
            bfr[i] = *(const short8*)(&Bs[cur][(wc + i * 16 + l16) * 36 + lk * 8]);
        }
        #pragma unroll
        for (int i = 0; i < 4; ++i)
            #pragma unroll
            for (int j = 0; j < 4; ++j)
                acc[i][j] = __builtin_amdgcn_mfma_f32_16x16x32_bf16(a[i], bfr[j], acc[i][j], 0, 0, 0);

        if (t + 1 < NT) {
            #pragma unroll
            for (int c = 0; c < 4; ++c) {
                u16x4 pk = {f2bu(bw[0][c]), f2bu(bw[1][c]), f2bu(bw[2][c]), f2bu(bw[3][c])};
                *(u16x4*)(&Bs[nx][(n4 + c) * 36 + kq]) = pk;
            }
        }
        asm volatile("s_waitcnt vmcnt(0) lgkmcnt(0)" ::: "memory");
        __builtin_amdgcn_s_barrier();
    }

    #pragma unroll
    for (int j = 0; j < 4; ++j) {
        int n = n0 + wc + j * 16 + l16;
        float bias = blm[n];
        #pragma unroll
        for (int i = 0; i < 4; ++i) {
            #pragma unroll
            for (int r2 = 0; r2 < 4; ++r2) {
                int m = m0 + wr + i * 16 + lk * 4 + r2;
                if (m < B_ * NMASK_)
                    out[(size_t)m * V_ + n] = acc[i][j][r2] + bias;
            }
        }
    }
}

// ---------------- Flash-style MFMA attention v5: QBLK=64, XCD-swizzled (green r13) ----------------
__global__ __launch_bounds__(256, 4)
void k_attn_mfma(const ushortT* __restrict__ qb, const ushortT* __restrict__ kb,
                 const ushortT* __restrict__ vb, const int* __restrict__ attn_mask,
                 float* __restrict__ x2) {
    int lin = (blockIdx.x & 7) * 192 + (blockIdx.x >> 3);
    int qt = lin & 7, bh = lin >> 3;
    int b = bh / H_, h = bh % H_;
    int tid = threadIdx.x, lane = tid & 63, w = tid >> 6;
    int l16 = lane & 15, lk = lane >> 4;

    __shared__ ushortT QP[64][72];      // Q tile; reused as P (wave w owns rows w*16..w*16+15)
    __shared__ ushortT Ks[64][72];
    __shared__ ushortT Vts[64][72];     // Vts[d][key]
    __shared__ float mskS[64];

    const ushortT* Qg = qb + ((size_t)bh * T_ + qt * 64) * HS_;
    #pragma unroll
    for (int i = 0; i < 2; ++i) {
        int slot = tid + i * 256;            // 0..511
        int r = slot >> 3, c8 = (slot & 7) * 8;
        *(u32x4*)(&QP[r][c8]) = *(const u32x4*)(Qg + (size_t)r * HS_ + c8);
    }
    if (tid < 64)
        mskS[tid] = attn_mask[b * T_ + qt * 64 + tid] ? 0.125f : 0.0f;
    __syncthreads();

    short8 aq[2];
    #pragma unroll
    for (int ks = 0; ks < 2; ++ks)
        aq[ks] = *(const short8*)(&QP[w * 16 + l16][ks * 32 + lk * 8]);
    float mrow[4];
    #pragma unroll
    for (int r = 0; r < 4; ++r)
        mrow[r] = mskS[w * 16 + lk * 4 + r];

    float lsum[4];
    f32x4 accO[4];
    #pragma unroll
    for (int r = 0; r < 4; ++r) lsum[r] = 0.f;
    #pragma unroll
    for (int j = 0; j < 4; ++j)
        accO[j] = (f32x4){0.f, 0.f, 0.f, 0.f};

    for (int kt = 0; kt < 8; ++kt) {
        __syncthreads();
        {
            int r = tid >> 2, c = (tid & 3) * 16;
            const ushortT* Kg = kb + ((size_t)bh * T_ + kt * 64 + r) * HS_ + c;
            *(u32x4*)(&Ks[r][c])     = *(const u32x4*)(Kg);
            *(u32x4*)(&Ks[r][c + 8]) = *(const u32x4*)(Kg + 8);
        }
        {
            int r = lane;
            int c = w * 16;
            const ushortT* Vg = vb + ((size_t)bh * T_ + kt * 64 + r) * HS_ + c;
            short8 v0 = *(const short8*)(Vg);
            short8 v1 = *(const short8*)(Vg + 8);
            #pragma unroll
            for (int e = 0; e < 8; ++e) Vts[c + e][r]     = (ushortT)v0[e];
            #pragma unroll
            for (int e = 0; e < 8; ++e) Vts[c + 8 + e][r] = (ushortT)v1[e];
        }
        __syncthreads();

        f32x4 accS[4];
        #pragma unroll
        for (int j = 0; j < 4; ++j)
            accS[j] = (f32x4){0.f, 0.f, 0.f, 0.f};
        #pragma unroll
        for (int ks = 0; ks < 2; ++ks) {
            short8 bk[4];
            #pragma unroll
            for (int j = 0; j < 4; ++j)
                bk[j] = *(const short8*)(&Ks[j * 16 + l16][ks * 32 + lk * 8]);
            #pragma unroll
            for (int j = 0; j < 4; ++j)
                accS[j] = __builtin_amdgcn_mfma_f32_16x16x32_bf16(aq[ks], bk[j], accS[j], 0, 0, 0);
        }

        #pragma unroll
        for (int r = 0; r < 4; ++r) {
            int rowl = lk * 4 + r;
            float m = mrow[r];
            float p0 = __expf(accS[0][r] * m);
            float p1 = __expf(accS[1][r] * m);
            float p2 = __expf(accS[2][r] * m);
            float p3 = __expf(accS[3][r] * m);
            lsum[r] += (p0 + p1) + (p2 + p3);
            QP[w * 16 + rowl][0 * 16 + l16] = f2bu(p0);
            QP[w * 16 + rowl][1 * 16 + l16] = f2bu(p1);
            QP[w * 16 + rowl][2 * 16 + l16] = f2bu(p2);
            QP[w * 16 + rowl][3 * 16 + l16] = f2bu(p3);
        }

        #pragma unroll
        for (int ks2 = 0; ks2 < 2; ++ks2) {
            short8 ap = *(const short8*)(&QP[w * 16 + l16][ks2 * 32 + lk * 8]);
            short8 bv[4];
            #pragma unroll
            for (int j = 0; j < 4; ++j)
                bv[j] = *(const short8*)(&Vts[j * 16 + l16][ks2 * 32 + lk * 8]);
            #pragma unroll
            for (int j = 0; j < 4; ++j)
                accO[j] = __builtin_amdgcn_mfma_f32_16x16x32_bf16(ap, bv[j], accO[j], 0, 0, 0);
        }
    }

    #pragma unroll
    for (int r = 0; r < 4; ++r) {
        float s = lsum[r];
        #pragma unroll
        for (int off = 1; off < 16; off <<= 1)
            s += __shfl_xor(s, off);
        float inv = 1.0f / s;
        int t = qt * 64 + w * 16 + lk * 4 + r;
        float* outp = x2 + ((size_t)b * T_ + t) * D_ + h * HS_;
        #pragma unroll
        for (int j = 0; j < 4; ++j)
            outp[j * 16 + l16] = accO[j][r] * inv;
    }
}

// ---------------- Classifier head: one block per b, parallel reduction ----------------
__global__ void k_cls(const float* __restrict__ x2, const float* __restrict__ Wc,
                      const float* __restrict__ bc, float* __restrict__ out) {
    int b = blockIdx.x;
    int tid = threadIdx.x;
    __shared__ float red0[4], red1[4];
    float a0 = 0.f, a1 = 0.f;
    const float* xr = x2 + (size_t)b * T_ * D_;
    for (int d = tid; d < D_; d += 256) {
        float x = xr[d];
        a0 += x * Wc[d * 2];
        a1 += x * Wc[d * 2 + 1];
    }
    #pragma unroll
    for (int o = 32; o > 0; o >>= 1) {
        a0 += __shfl_down(a0, o);
        a1 += __shfl_down(a1, o);
    }
    if ((tid & 63) == 0) { red0[tid >> 6] = a0; red1[tid >> 6] = a1; }
    __syncthreads();
    if (tid == 0)
        out[b * 2]     = red0[0] + red0[1] + red0[2] + red0[3] + bc[0];
    if (tid == 1)
        out[b * 2 + 1] = red1[0] + red1[1] + red1[2] + red1[3] + bc[1];
}

extern "C" void kernel_launch(void* const* d_in, const int* in_sizes, int n_in,
                              void* d_out, int out_size, void* d_ws, size_t ws_size,
                              hipStream_t stream) {
    const int* seq        = (const int*)d_in[0];
    const int* seg        = (const int*)d_in[1];
    const int* attn_mask  = (const int*)d_in[2];
    const int* masked_pos = (const int*)d_in[3];
    const float* tok  = (const float*)d_in[4];
    const float* sege = (const float*)d_in[5];
    const float* pos  = (const float*)d_in[6];
    const float* ln_g = (const float*)d_in[7];
    const float* ln_b = (const float*)d_in[8];
    const float* Wq   = (const float*)d_in[9];
    const float* Wk   = (const float*)d_in[10];
    const float* Wv   = (const float*)d_in[11];
    const float* Wlm  = (const float*)d_in[12];
    const float* blm  = (const float*)d_in[13];
    const float* Wc   = (const float*)d_in[14];
    const float* bc   = (const float*)d_in[15];

    float* out_lm  = (float*)d_out;                       // [B, NMASK, V]
    float* out_cls = out_lm + (size_t)B_ * NMASK_ * V_;   // [B, 2]

    const size_t XSZ = (size_t)B_ * T_ * D_;              // 6,291,456
    float* ws = (float*)d_ws;
    float*   x2   = ws;                                   // f32, 25.2 MB
    ushortT* base = (ushortT*)(ws + XSZ);                 // bf16 region
    ushortT* xb    = base;                                // [8192][768]
    ushortT* qb    = base + XSZ;                          // [bh][t][64]
    ushortT* kb    = base + 2 * XSZ;                      // [bh][t][64]
    ushortT* vb    = base + 3 * XSZ;                      // [bh][t][64]
    ushortT* WcatT = base + 4 * XSZ;                      // [2304][768]
    ushortT* xm    = base;                                // [384][768] (xb dead by then)

    k_embed_ln<<<B_ * T_, 192, 0, stream>>>(seq, seg, tok, sege, pos, ln_g, ln_b, xb);
    k_prep_wqkv<<<dim3(3 * H_, 12), 256, 0, stream>>>(Wq, Wk, Wv, WcatT);
    k_gemm_qkv<<<1152, 256, 0, stream>>>(xb, WcatT, qb, kb, vb);
    k_attn_mfma<<<192 * 8, 256, 0, stream>>>(qb, kb, vb, attn_mask, x2);
    k_gather_xm<<<384, 256, 0, stream>>>(x2, masked_pos, xm);
    k_gemm_lm<<<750, 256, 0, stream>>>(xm, Wlm, blm, out_lm);
    k_cls<<<B_, 256, 0, stream>>>(x2, Wc, bc, out_cls);
}

// Round 19
// 146.990 us; speedup vs baseline: 1.0350x; 1.0350x over previous
//
#include <hip/hip_runtime.h>
#include <hip/hip_bf16.h>

#define V_     32000
#define NSEG_  2
#define MAXLEN_ 512
#define D_     768
#define H_     12
#define HS_    64
#define B_     16
#define T_     512
#define NMASK_ 20
#define LN_EPS_ 1e-5f

typedef __hip_bfloat16 bf16;
typedef unsigned short ushortT;
typedef __attribute__((ext_vector_type(8))) short short8;
typedef __attribute__((ext_vector_type(4))) float f32x4;
typedef __attribute__((ext_vector_type(4))) unsigned int u32x4;
typedef __attribute__((ext_vector_type(4))) unsigned short u16x4;

__device__ __forceinline__ ushortT f2bu(float f) {
    bf16 h = __float2bfloat16(f);
    return *reinterpret_cast<ushortT*>(&h);
}

// ---------------- Kernel 1: embedding gather + LayerNorm -> xb (bf16), vectorized ----------------
__global__ void k_embed_ln(const int* __restrict__ seq, const int* __restrict__ seg,
                           const float* __restrict__ tok, const float* __restrict__ sege,
                           const float* __restrict__ pos, const float* __restrict__ g,
                           const float* __restrict__ bb, ushortT* __restrict__ xb) {
    int row = blockIdx.x;          // b*T + t
    int t = row & (T_ - 1);
    int tid = threadIdx.x;         // 0..191
    __shared__ float wsum[3], wsq[3];

    int sidx = seq[row];
    int gidx = seg[row];

    f32x4 e = *(const f32x4*)(tok  + (size_t)sidx * D_ + tid * 4);
    f32x4 e2 = *(const f32x4*)(sege + (size_t)gidx * D_ + tid * 4);
    f32x4 e3 = *(const f32x4*)(pos  + (size_t)t    * D_ + tid * 4);
    e = e + e2 + e3;

    float ls = e.x + e.y + e.z + e.w;
    float lq = e.x * e.x + e.y * e.y + e.z * e.z + e.w * e.w;
    #pragma unroll
    for (int o = 32; o > 0; o >>= 1) {
        ls += __shfl_down(ls, o);
        lq += __shfl_down(lq, o);
    }
    if ((tid & 63) == 0) { wsum[tid >> 6] = ls; wsq[tid >> 6] = lq; }
    __syncthreads();
    float s  = wsum[0] + wsum[1] + wsum[2];
    float sq = wsq[0] + wsq[1] + wsq[2];
    float mean = s * (1.0f / D_);
    float var  = sq * (1.0f / D_) - mean * mean;
    float rstd = rsqrtf(var + LN_EPS_);

    f32x4 g4 = *(const f32x4*)(g  + tid * 4);
    f32x4 b4 = *(const f32x4*)(bb + tid * 4);
    f32x4 x4;
    x4.x = (e.x - mean) * rstd * g4.x + b4.x;
    x4.y = (e.y - mean) * rstd * g4.y + b4.y;
    x4.z = (e.z - mean) * rstd * g4.z + b4.z;
    x4.w = (e.w - mean) * rstd * g4.w + b4.w;
    u16x4 ov = {f2bu(x4.x), f2bu(x4.y), f2bu(x4.z), f2bu(x4.w)};
    *(u16x4*)(xb + (size_t)row * D_ + tid * 4) = ov;
}

// ---------------- Prep: WcatT[n][k] bf16; grid (36, 12) ----------------
__global__ void k_prep_wqkv(const float* __restrict__ Wq, const float* __restrict__ Wk,
                            const float* __restrict__ Wv, ushortT* __restrict__ Wt) {
    int blk = blockIdx.x;
    int which = blk / H_, h = blk % H_;
    int kc = blockIdx.y * 64;
    const float* W = (which == 0) ? Wq : (which == 1) ? Wk : Wv;  // [H][D][HS]
    __shared__ float tile[64][65];
    int tid = threadIdx.x, c = tid & 63, rgrp = tid >> 6;
    for (int kk = rgrp; kk < 64; kk += 4)
        tile[kk][c] = W[((size_t)h * D_ + kc + kk) * HS_ + c];
    __syncthreads();
    for (int ss = rgrp; ss < 64; ss += 4)
        Wt[((size_t)which * D_ + h * HS_ + ss) * D_ + kc + c] = f2bu(tile[c][ss]);
}

// ---------------- Prep: gather masked rows -> xm[384][768] bf16 (zero pad) ----------------
__global__ void k_gather_xm(const float* __restrict__ x2, const int* __restrict__ masked_pos,
                            ushortT* __restrict__ xm) {
    int r = blockIdx.x;      // 0..383
    int tid = threadIdx.x;
    if (r < B_ * NMASK_) {
        int b = r / NMASK_, m = r % NMASK_;
        int t = masked_pos[b * NMASK_ + m];
        for (int d = tid; d < D_; d += 256)
            xm[(size_t)r * D_ + d] = f2bu(x2[((size_t)b * T_ + t) * D_ + d]);
    } else {
        for (int d = tid; d < D_; d += 256)
            xm[(size_t)r * D_ + d] = 0;
    }
}

// ---------------- shared staging helpers ----------------
__device__ __forceinline__ void stage_chunk(const ushortT* __restrict__ src, int row_stride,
                                            int r0, int k0, ushortT* dst, int w, int lane) {
    #pragma unroll
    for (int i = 0; i < 2; ++i) {
        int slot = w * 64 + lane + i * 256;    // 0..511
        int row = slot >> 2;
        int cs = ((slot & 3) ^ (row & 3)) * 8; // swizzled source chunk (rule 21)
        __builtin_amdgcn_global_load_lds(
            (const __attribute__((address_space(1))) void*)(src + (size_t)(r0 + row) * row_stride + k0 + cs),
            (__attribute__((address_space(3))) void*)(dst + (w * 64 + i * 256) * 8),
            16, 0, 0);
    }
}

// ---------------- 2-phase double-buffered MFMA 128x128 GEMM body, chunk-swizzled ----------------
__device__ __forceinline__ void gemm128_2ph(const ushortT* __restrict__ A,
                                            const ushortT* __restrict__ Bt,
                                            int m0, int n0,
                                            ushortT* lds,       // >= 16384 ushorts
                                            f32x4 acc[4][4]) {
    const int NT = D_ / 32;   // 24
    int tid = threadIdx.x;
    int lane = tid & 63, w = tid >> 6;
    int wr = (w >> 1) * 64, wc = (w & 1) * 64;
    int l16 = lane & 15, lk = lane >> 4;
    int sw = (lk ^ (l16 & 3)) * 8;            // swizzled read chunk offset (ushorts)

    #pragma unroll
    for (int i = 0; i < 4; ++i)
        #pragma unroll
        for (int j = 0; j < 4; ++j)
            acc[i][j] = (f32x4){0.f, 0.f, 0.f, 0.f};

    stage_chunk(A, D_, m0, 0, lds, w, lane);
    stage_chunk(Bt, D_, n0, 0, lds + 4096, w, lane);
    asm volatile("s_waitcnt vmcnt(0)" ::: "memory");
    __builtin_amdgcn_s_barrier();

    for (int t = 0; t < NT; ++t) {
        int cur = (t & 1) * 8192;
        int nxt = 8192 - cur;
        if (t + 1 < NT) {
            stage_chunk(A, D_, m0, (t + 1) * 32, lds + nxt, w, lane);
            stage_chunk(Bt, D_, n0, (t + 1) * 32, lds + nxt + 4096, w, lane);
        }

        const ushortT* Asc = lds + cur;
        const ushortT* Bsc = lds + cur + 4096;
        short8 a[4], bfr[4];
        #pragma unroll
        for (int i = 0; i < 4; ++i) {
            a[i]   = *(const short8*)(Asc + (wr + i * 16 + l16) * 32 + sw);
            bfr[i] = *(const short8*)(Bsc + (wc + i * 16 + l16) * 32 + sw);
        }
        #pragma unroll
        for (int i = 0; i < 4; ++i)
            #pragma unroll
            for (int j = 0; j < 4; ++j)
                acc[i][j] = __builtin_amdgcn_mfma_f32_16x16x32_bf16(a[i], bfr[j], acc[i][j], 0, 0, 0);

        asm volatile("s_waitcnt vmcnt(0)" ::: "memory");
        __builtin_amdgcn_s_barrier();
    }
}

// ---------------- QKV GEMM: XCD-swizzled grid 1152; LDS-transposed coalesced epilogue ----------------
__global__ __launch_bounds__(256, 4)
void k_gemm_qkv(const ushortT* __restrict__ xb, const ushortT* __restrict__ WcatT,
                ushortT* __restrict__ qb, ushortT* __restrict__ kb,
                ushortT* __restrict__ vb) {
    __shared__ ushortT lds[128 * 136];   // gemm uses first 16384; epilogue uses all
    f32x4 acc[4][4];
    int lin = (blockIdx.x & 7) * 144 + (blockIdx.x >> 3);
    int n0 = (lin % 18) * 128, m0 = (lin / 18) * 128;
    gemm128_2ph(xb, WcatT, m0, n0, lds, acc);

    int tid = threadIdx.x;
    int lane = tid & 63, w = tid >> 6;
    int wr = (w >> 1) * 64, wc = (w & 1) * 64;
    int l16 = lane & 15, lk = lane >> 4;

    #pragma unroll
    for (int j = 0; j < 4; ++j) {
        int n = wc + j * 16 + l16;
        #pragma unroll
        for (int i = 0; i < 4; ++i) {
            #pragma unroll
            for (int r = 0; r < 4; ++r) {
                int m = wr + i * 16 + lk * 4 + r;
                lds[m * 136 + n] = f2bu(acc[i][j][r]);
            }
        }
    }
    __syncthreads();

    int which = n0 / D_;                 // uniform per block
    int nrem0 = n0 - which * D_;
    ushortT* outp = (which == 0) ? qb : (which == 1) ? kb : vb;
    int b = m0 >> 9;
    int t0 = m0 & (T_ - 1);
    #pragma unroll
    for (int p = 0; p < 8; ++p) {
        int chunk = p * 256 + tid;       // 0..2047
        int row = chunk >> 4;            // m local
        int nc = (chunk & 15) * 8;       // n ushort offset
        int h = (nrem0 >> 6) + (nc >> 6);
        int s0 = nc & 63;
        u32x4 v = *(const u32x4*)(&lds[row * 136 + nc]);
        *(u32x4*)(outp + ((size_t)(b * H_ + h) * T_ + (t0 + row)) * HS_ + s0) = v;
    }
}

// ---------------- LM GEMM (fused transpose), XCD-grouped, 3-buffer A + depth-2 B prefetch ----------------
// Per K-step: MFMA(t) -> issue A(t+2) gload (into As3[(t+2)%3], disjoint from this iter's
// reads) + B(t+2) loads (bw[cur]) -> ds_write B(t+1) from bw[nx] (counted dep-wait; A(t+2)/
// B(t+2) stay in flight) -> lgkmcnt(0) + barrier (no VMEM drain at the barrier).
__global__ __launch_bounds__(256, 3)
void k_gemm_lm(const ushortT* __restrict__ xm, const float* __restrict__ Wlm,
               const float* __restrict__ blm, float* __restrict__ out) {
    const int NT = D_ / 32;   // 24
    __shared__ ushortT As3[3][4096];
    __shared__ ushortT Bs[2][128 * 36];
    f32x4 acc[4][4];

    int bid = blockIdx.x;            // 0..749
    const int q = 93, r = 6;
    int xcd = bid & 7, idx = bid >> 3;
    int lin = (xcd < r) ? xcd * (q + 1) + idx : r * (q + 1) + (xcd - r) * q + idx;
    int nt = lin / 3, mt = lin - nt * 3;
    int m0 = mt * 128, n0 = nt * 128;

    int tid = threadIdx.x;
    int lane = tid & 63, w = tid >> 6;
    int wr = (w >> 1) * 64, wc = (w & 1) * 64;
    int l16 = lane & 15, lk = lane >> 4;
    int sw = (lk ^ (l16 & 3)) * 8;
    int n_l = tid & 127;            // B-staging lane -> n
    int kkg = tid >> 7;             // 0..1

    #pragma unroll
    for (int i = 0; i < 4; ++i)
        #pragma unroll
        for (int j = 0; j < 4; ++j)
            acc[i][j] = (f32x4){0.f, 0.f, 0.f, 0.f};

    const float* Wbase = Wlm + n0 + n_l;

    float bw0[16], bw1[16];
    // prologue: A(0) gload; B(0) -> bw0
    stage_chunk(xm, D_, m0, 0, As3[0], w, lane);
    #pragma unroll
    for (int g = 0; g < 4; ++g) {
        int kk0 = (g * 2 + kkg) * 4;
        const float* Wp = Wbase + (size_t)kk0 * V_;
        bw0[g * 4 + 0] = Wp[0];
        bw0[g * 4 + 1] = Wp[(size_t)V_];
        bw0[g * 4 + 2] = Wp[(size_t)2 * V_];
        bw0[g * 4 + 3] = Wp[(size_t)3 * V_];
    }
    asm volatile("s_waitcnt vmcnt(0)" ::: "memory");
    #pragma unroll
    for (int g = 0; g < 4; ++g) {
        int kk0 = (g * 2 + kkg) * 4;
        u16x4 pk = {f2bu(bw0[g * 4]), f2bu(bw0[g * 4 + 1]), f2bu(bw0[g * 4 + 2]), f2bu(bw0[g * 4 + 3])};
        *(u16x4*)(&Bs[0][n_l * 36 + kk0]) = pk;
    }
    // issue A(1) gload; B(1) -> bw1
    stage_chunk(xm, D_, m0, 32, As3[1], w, lane);
    #pragma unroll
    for (int g = 0; g < 4; ++g) {
        int kk0 = (g * 2 + kkg) * 4;
        const float* Wp = Wbase + (size_t)(32 + kk0) * V_;
        bw1[g * 4 + 0] = Wp[0];
        bw1[g * 4 + 1] = Wp[(size_t)V_];
        bw1[g * 4 + 2] = Wp[(size_t)2 * V_];
        bw1[g * 4 + 3] = Wp[(size_t)3 * V_];
    }
    asm volatile("s_waitcnt lgkmcnt(0)" ::: "memory");
    __builtin_amdgcn_s_barrier();
    // Loop invariant at iter t: As3[t%3]=A(t) landed; As3[(t+1)%3]<-A(t+1) in flight;
    // Bs[t&1]=B(t) written; bw[(t+1)&1]=B(t+1) in flight/landed.

    for (int t = 0; t < NT; ++t) {
        int cur = t & 1, nx = cur ^ 1;
        const ushortT* Ac = As3[t % 3];

        short8 a[4], bfr[4];
        #pragma unroll
        for (int i = 0; i < 4; ++i) {
            a[i]   = *(const short8*)(Ac + (wr + i * 16 + l16) * 32 + sw);
            bfr[i] = *(const short8*)(&Bs[cur][(wc + i * 16 + l16) * 36 + lk * 8]);
        }
        #pragma unroll
        for (int i = 0; i < 4; ++i)
            #pragma unroll
            for (int j = 0; j < 4; ++j)
                acc[i][j] = __builtin_amdgcn_mfma_f32_16x16x32_bf16(a[i], bfr[j], acc[i][j], 0, 0, 0);

        // issue next-next tile first so it stays in flight across the B(t+1) dep-wait
        if (t + 2 < NT) {
            stage_chunk(xm, D_, m0, (t + 2) * 32, As3[(t + 2) % 3], w, lane);
            int k0 = (t + 2) * 32;
            if (cur == 0) {
                #pragma unroll
                for (int g = 0; g < 4; ++g) {
                    int kk0 = (g * 2 + kkg) * 4;
                    const float* Wp = Wbase + (size_t)(k0 + kk0) * V_;
                    bw0[g * 4 + 0] = Wp[0];
                    bw0[g * 4 + 1] = Wp[(size_t)V_];
                    bw0[g * 4 + 2] = Wp[(size_t)2 * V_];
                    bw0[g * 4 + 3] = Wp[(size_t)3 * V_];
                }
            } else {
                #pragma unroll
                for (int g = 0; g < 4; ++g) {
                    int kk0 = (g * 2 + kkg) * 4;
                    const float* Wp = Wbase + (size_t)(k0 + kk0) * V_;
                    bw1[g * 4 + 0] = Wp[0];
                    bw1[g * 4 + 1] = Wp[(size_t)V_];
                    bw1[g * 4 + 2] = Wp[(size_t)2 * V_];
                    bw1[g * 4 + 3] = Wp[(size_t)3 * V_];
                }
            }
        }
        // ds_write B(t+1) (registers issued a full iteration ago)
        if (t + 1 < NT) {
            if (nx == 0) {
                #pragma unroll
                for (int g = 0; g < 4; ++g) {
                    int kk0 = (g * 2 + kkg) * 4;
                    u16x4 pk = {f2bu(bw0[g * 4]), f2bu(bw0[g * 4 + 1]), f2bu(bw0[g * 4 + 2]), f2bu(bw0[g * 4 + 3])};
                    *(u16x4*)(&Bs[0][n_l * 36 + kk0]) = pk;
                }
            } else {
                #pragma unroll
                for (int g = 0; g < 4; ++g) {
                    int kk0 = (g * 2 + kkg) * 4;
                    u16x4 pk = {f2bu(bw1[g * 4]), f2bu(bw1[g * 4 + 1]), f2bu(bw1[g * 4 + 2]), f2bu(bw1[g * 4 + 3])};
                    *(u16x4*)(&Bs[1][n_l * 36 + kk0]) = pk;
                }
            }
        }
        asm volatile("s_waitcnt lgkmcnt(0)" ::: "memory");
        __builtin_amdgcn_s_barrier();
    }

    #pragma unroll
    for (int j = 0; j < 4; ++j) {
        int n = n0 + wc + j * 16 + l16;
        float bias = blm[n];
        #pragma unroll
        for (int i = 0; i < 4; ++i) {
            #pragma unroll
            for (int r2 = 0; r2 < 4; ++r2) {
                int m = m0 + wr + i * 16 + lk * 4 + r2;
                if (m < B_ * NMASK_)
                    out[(size_t)m * V_ + n] = acc[i][j][r2] + bias;
            }
        }
    }
}

// ---------------- Flash-style MFMA attention v5: QBLK=64, XCD-swizzled (green r13) ----------------
__global__ __launch_bounds__(256, 4)
void k_attn_mfma(const ushortT* __restrict__ qb, const ushortT* __restrict__ kb,
                 const ushortT* __restrict__ vb, const int* __restrict__ attn_mask,
                 float* __restrict__ x2) {
    int lin = (blockIdx.x & 7) * 192 + (blockIdx.x >> 3);
    int qt = lin & 7, bh = lin >> 3;
    int b = bh / H_, h = bh % H_;
    int tid = threadIdx.x, lane = tid & 63, w = tid >> 6;
    int l16 = lane & 15, lk = lane >> 4;

    __shared__ ushortT QP[64][72];      // Q tile; reused as P (wave w owns rows w*16..w*16+15)
    __shared__ ushortT Ks[64][72];
    __shared__ ushortT Vts[64][72];     // Vts[d][key]
    __shared__ float mskS[64];

    const ushortT* Qg = qb + ((size_t)bh * T_ + qt * 64) * HS_;
    #pragma unroll
    for (int i = 0; i < 2; ++i) {
        int slot = tid + i * 256;            // 0..511
        int r = slot >> 3, c8 = (slot & 7) * 8;
        *(u32x4*)(&QP[r][c8]) = *(const u32x4*)(Qg + (size_t)r * HS_ + c8);
    }
    if (tid < 64)
        mskS[tid] = attn_mask[b * T_ + qt * 64 + tid] ? 0.125f : 0.0f;
    __syncthreads();

    short8 aq[2];
    #pragma unroll
    for (int ks = 0; ks < 2; ++ks)
        aq[ks] = *(const short8*)(&QP[w * 16 + l16][ks * 32 + lk * 8]);
    float mrow[4];
    #pragma unroll
    for (int r = 0; r < 4; ++r)
        mrow[r] = mskS[w * 16 + lk * 4 + r];

    float lsum[4];
    f32x4 accO[4];
    #pragma unroll
    for (int r = 0; r < 4; ++r) lsum[r] = 0.f;
    #pragma unroll
    for (int j = 0; j < 4; ++j)
        accO[j] = (f32x4){0.f, 0.f, 0.f, 0.f};

    for (int kt = 0; kt < 8; ++kt) {
        __syncthreads();
        {
            int r = tid >> 2, c = (tid & 3) * 16;
            const ushortT* Kg = kb + ((size_t)bh * T_ + kt * 64 + r) * HS_ + c;
            *(u32x4*)(&Ks[r][c])     = *(const u32x4*)(Kg);
            *(u32x4*)(&Ks[r][c + 8]) = *(const u32x4*)(Kg + 8);
        }
        {
            int r = lane;
            int c = w * 16;
            const ushortT* Vg = vb + ((size_t)bh * T_ + kt * 64 + r) * HS_ + c;
            short8 v0 = *(const short8*)(Vg);
            short8 v1 = *(const short8*)(Vg + 8);
            #pragma unroll
            for (int e = 0; e < 8; ++e) Vts[c + e][r]     = (ushortT)v0[e];
            #pragma unroll
            for (int e = 0; e < 8; ++e) Vts[c + 8 + e][r] = (ushortT)v1[e];
        }
        __syncthreads();

        f32x4 accS[4];
        #pragma unroll
        for (int j = 0; j < 4; ++j)
            accS[j] = (f32x4){0.f, 0.f, 0.f, 0.f};
        #pragma unroll
        for (int ks = 0; ks < 2; ++ks) {
            short8 bk[4];
            #pragma unroll
            for (int j = 0; j < 4; ++j)
                bk[j] = *(const short8*)(&Ks[j * 16 + l16][ks * 32 + lk * 8]);
            #pragma unroll
            for (int j = 0; j < 4; ++j)
                accS[j] = __builtin_amdgcn_mfma_f32_16x16x32_bf16(aq[ks], bk[j], accS[j], 0, 0, 0);
        }

        #pragma unroll
        for (int r = 0; r < 4; ++r) {
            int rowl = lk * 4 + r;
            float m = mrow[r];
            float p0 = __expf(accS[0][r] * m);
            float p1 = __expf(accS[1][r] * m);
            float p2 = __expf(accS[2][r] * m);
            float p3 = __expf(accS[3][r] * m);
            lsum[r] += (p0 + p1) + (p2 + p3);
            QP[w * 16 + rowl][0 * 16 + l16] = f2bu(p0);
            QP[w * 16 + rowl][1 * 16 + l16] = f2bu(p1);
            QP[w * 16 + rowl][2 * 16 + l16] = f2bu(p2);
            QP[w * 16 + rowl][3 * 16 + l16] = f2bu(p3);
        }

        #pragma unroll
        for (int ks2 = 0; ks2 < 2; ++ks2) {
            short8 ap = *(const short8*)(&QP[w * 16 + l16][ks2 * 32 + lk * 8]);
            short8 bv[4];
            #pragma unroll
            for (int j = 0; j < 4; ++j)
                bv[j] = *(const short8*)(&Vts[j * 16 + l16][ks2 * 32 + lk * 8]);
            #pragma unroll
            for (int j = 0; j < 4; ++j)
                accO[j] = __builtin_amdgcn_mfma_f32_16x16x32_bf16(ap, bv[j], accO[j], 0, 0, 0);
        }
    }

    #pragma unroll
    for (int r = 0; r < 4; ++r) {
        float s = lsum[r];
        #pragma unroll
        for (int off = 1; off < 16; off <<= 1)
            s += __shfl_xor(s, off);
        float inv = 1.0f / s;
        int t = qt * 64 + w * 16 + lk * 4 + r;
        float* outp = x2 + ((size_t)b * T_ + t) * D_ + h * HS_;
        #pragma unroll
        for (int j = 0; j < 4; ++j)
            outp[j * 16 + l16] = accO[j][r] * inv;
    }
}

// ---------------- Classifier head: one block per b, parallel reduction ----------------
__global__ void k_cls(const float* __restrict__ x2, const float* __restrict__ Wc,
                      const float* __restrict__ bc, float* __restrict__ out) {
    int b = blockIdx.x;
    int tid = threadIdx.x;
    __shared__ float red0[4], red1[4];
    float a0 = 0.f, a1 = 0.f;
    const float* xr = x2 + (size_t)b * T_ * D_;
    for (int d = tid; d < D_; d += 256) {
        float x = xr[d];
        a0 += x * Wc[d * 2];
        a1 += x * Wc[d * 2 + 1];
    }
    #pragma unroll
    for (int o = 32; o > 0; o >>= 1) {
        a0 += __shfl_down(a0, o);
        a1 += __shfl_down(a1, o);
    }
    if ((tid & 63) == 0) { red0[tid >> 6] = a0; red1[tid >> 6] = a1; }
    __syncthreads();
    if (tid == 0)
        out[b * 2]     = red0[0] + red0[1] + red0[2] + red0[3] + bc[0];
    if (tid == 1)
        out[b * 2 + 1] = red1[0] + red1[1] + red1[2] + red1[3] + bc[1];
}

extern "C" void kernel_launch(void* const* d_in, const int* in_sizes, int n_in,
                              void* d_out, int out_size, void* d_ws, size_t ws_size,
                              hipStream_t stream) {
    const int* seq        = (const int*)d_in[0];
    const int* seg        = (const int*)d_in[1];
    const int* attn_mask  = (const int*)d_in[2];
    const int* masked_pos = (const int*)d_in[3];
    const float* tok  = (const float*)d_in[4];
    const float* sege = (const float*)d_in[5];
    const float* pos  = (const float*)d_in[6];
    const float* ln_g = (const float*)d_in[7];
    const float* ln_b = (const float*)d_in[8];
    const float* Wq   = (const float*)d_in[9];
    const float* Wk   = (const float*)d_in[10];
    const float* Wv   = (const float*)d_in[11];
    const float* Wlm  = (const float*)d_in[12];
    const float* blm  = (const float*)d_in[13];
    const float* Wc   = (const float*)d_in[14];
    const float* bc   = (const float*)d_in[15];

    float* out_lm  = (float*)d_out;                       // [B, NMASK, V]
    float* out_cls = out_lm + (size_t)B_ * NMASK_ * V_;   // [B, 2]

    const size_t XSZ = (size_t)B_ * T_ * D_;              // 6,291,456
    float* ws = (float*)d_ws;
    float*   x2   = ws;                                   // f32, 25.2 MB
    ushortT* base = (ushortT*)(ws + XSZ);                 // bf16 region
    ushortT* xb    = base;                                // [8192][768]
    ushortT* qb    = base + XSZ;                          // [bh][t][64]
    ushortT* kb    = base + 2 * XSZ;                      // [bh][t][64]
    ushortT* vb    = base + 3 * XSZ;                      // [bh][t][64]
    ushortT* WcatT = base + 4 * XSZ;                      // [2304][768]
    ushortT* xm    = base;                                // [384][768] (xb dead by then)

    k_embed_ln<<<B_ * T_, 192, 0, stream>>>(seq, seg, tok, sege, pos, ln_g, ln_b, xb);
    k_prep_wqkv<<<dim3(3 * H_, 12), 256, 0, stream>>>(Wq, Wk, Wv, WcatT);
    k_gemm_qkv<<<1152, 256, 0, stream>>>(xb, WcatT, qb, kb, vb);
    k_attn_mfma<<<192 * 8, 256, 0, stream>>>(qb, kb, vb, attn_mask, x2);
    k_gather_xm<<<384, 256, 0, stream>>>(x2, masked_pos, xm);
    k_gemm_lm<<<750, 256, 0, stream>>>(xm, Wlm, blm, out_lm);
    k_cls<<<B_, 256, 0, stream>>>(x2, Wc, bc, out_cls);
}